// Round 6
// baseline (167.740 us; speedup 1.0000x reference)
//
#include <hip/hip_runtime.h>

#define LL   8192   // sequence length
#define CC   2048   // channels
#define FF   128    // inner dim of g@kernel
#define KK   257    // taps
#define PAD  128    // (KK-1)/2

#define SROWP 328   // synEb row stride (u16): 32 zeros | 257 taps | 31 zeros | 8 pad (164 dw)
#define NT   9      // K-steps of 32 (16x16x32 MFMA)

#define LPAD   8512 // xT row (u16): l in [-128, 8384); 133 64-l tiles; max read idx 8463
#define LTILES 133

// fallback (R5, harness-verified) constants
#define NCH  4
#define NW   4
#define ROWS 1352

typedef __bf16 bf16x8 __attribute__((ext_vector_type(8)));
typedef float  f32x4  __attribute__((ext_vector_type(4)));

static __device__ __forceinline__ unsigned short f2bf(float f) {
    unsigned u = __float_as_uint(f);
    u = (u + 0x7fffu + ((u >> 16) & 1u)) >> 16;   // RNE
    return (unsigned short)u;
}

// Build synEb[c][328] bf16: zeros | g[c,:]@kernel[:,k] | zeros (incl. pad), with the
// Yt-row override folded in as a delta kernel (tap=1 at k=128).
__global__ __launch_bounds__(256) void synb_kernel(const float* __restrict__ g,
                                                   const float* __restrict__ kern,
                                                   const int* __restrict__ Yt, int ny,
                                                   unsigned short* __restrict__ synEb) {
    __shared__ int sfl[4];
    const int c0 = blockIdx.x * 4;
    const int t  = threadIdx.x;
    if (t < 4) sfl[t] = 0;
    __syncthreads();
    for (int i = t; i < ny; i += 256) {
        int y = Yt[i];
        #pragma unroll
        for (int ii = 0; ii < 4; ++ii) if (y == c0 + ii) sfl[ii] = 1;
    }
    __syncthreads();
    const float* g0 = g + (size_t)(c0 + 0) * FF;
    const float* g1 = g + (size_t)(c0 + 1) * FF;
    const float* g2 = g + (size_t)(c0 + 2) * FF;
    const float* g3 = g + (size_t)(c0 + 3) * FF;
    const int fl0 = sfl[0], fl1 = sfl[1], fl2 = sfl[2], fl3 = sfl[3];
    for (int p = t; p < SROWP; p += 256) {
        const int kk = p - 32;
        float a0 = 0.f, a1 = 0.f, a2 = 0.f, a3 = 0.f;
        const bool inr = (kk >= 0) && (kk < KK);
        if (inr) {
            #pragma unroll 8
            for (int f = 0; f < FF; ++f) {
                float kv = kern[f * KK + kk];      // coalesced across p
                a0 += kv * g0[f];
                a1 += kv * g1[f];
                a2 += kv * g2[f];
                a3 += kv * g3[f];
            }
        }
        float dlt = (kk == PAD) ? 1.f : 0.f;
        float v0 = inr ? (fl0 ? dlt : a0) : 0.f;
        float v1 = inr ? (fl1 ? dlt : a1) : 0.f;
        float v2 = inr ? (fl2 ? dlt : a2) : 0.f;
        float v3 = inr ? (fl3 ? dlt : a3) : 0.f;
        synEb[(size_t)(c0 + 0) * SROWP + p] = f2bf(v0);
        synEb[(size_t)(c0 + 1) * SROWP + p] = f2bf(v1);
        synEb[(size_t)(c0 + 2) * SROWP + p] = f2bf(v2);
        synEb[(size_t)(c0 + 3) * SROWP + p] = f2bf(v3);
    }
}

// ---- one-time transpose+convert: x (L,C) fp32 -> xT (C, LPAD) bf16 -------------
// xT[c][l+128] = bf16(x[l][c]) for l in [0,LL), zero elsewhere. Tiled 64x64 via
// LDS; reads 256B/wave coalesced, writes 8 x 128B full lines per wave. Pure
// streaming both sides: ~98 MB total -> ~16-19 us.
__global__ __launch_bounds__(256) void xpose_kernel(const float* __restrict__ x,
                                                    unsigned short* __restrict__ xT) {
    __shared__ float tile[64][65];            // +1 pad: odd dword stride, no conflicts
    const int t  = threadIdx.x;
    const int lt = blockIdx.x;                // [0,133) l-tile over padded range
    const int C0 = blockIdx.y << 6;           // channel tile
    const int lb = (lt << 6) - 128;           // global l of tile row 0
    #pragma unroll
    for (int it = 0; it < 16; ++it) {
        int row = (it << 2) + (t >> 6);
        int l = lb + row;
        float v = 0.f;
        if ((unsigned)l < (unsigned)LL) v = x[(size_t)l * CC + C0 + (t & 63)];
        tile[row][t & 63] = v;
    }
    __syncthreads();
    #pragma unroll
    for (int h = 0; h < 2; ++h) {
        int c_loc = (t >> 3) + (h << 5);      // [0,64)
        int l0    = (t & 7) << 3;             // [0,64) step 8
        unsigned dd[4];
        #pragma unroll
        for (int i = 0; i < 4; ++i) {
            unsigned lo = f2bf(tile[l0 + 2 * i][c_loc]);
            unsigned hi = f2bf(tile[l0 + 2 * i + 1][c_loc]);
            dd[i] = lo | (hi << 16);
        }
        *(uint4*)(xT + (size_t)(C0 + c_loc) * LPAD + (lt << 6) + l0) =
            make_uint4(dd[0], dd[1], dd[2], dd[3]);
    }
}

// ---- streaming conv: no LDS, no barriers -------------------------------------
// Block = 4 waves; wave = 1 channel x 2048 outputs (2 window-iters of 1024).
// B (window-invariant) hoisted once into 36 VGPR via a global funnel read of
// synEb. A-fragment = ONE aligned global_load_dwordx4 from xT per MFMA: lane
// (n,q4) reads u16 [W0+256s+16n+8q4+32m .. +8) -- wave footprint ~5 cache
// lines, heavy L1 reuse, single base reg + immediate offsets. Verified mapping
// (R5 harness-pass): D col=n, row=4q4+r -> l = W0+256s+64q4+16r+n;
// B.u16[r] = row[8q4-n+32+32m+r]; tail taps (idx>=289) are zero so the A
// over-read window [1280,1295] contributes nothing.
__global__ __launch_bounds__(256, 4) void conv_stream(const unsigned short* __restrict__ xT,
                                                      const unsigned short* __restrict__ synEb,
                                                      float* __restrict__ out) {
    const int t  = threadIdx.x;
    const int c  = (blockIdx.y << 2) + (t >> 6);
    const int Lb = blockIdx.x << 11;          // 2048-l chunk
    const int ln = t & 63;
    const int n = ln & 15, q4 = ln >> 4;

    // ---- hoist B once: funnel from global synEb row (ib in [17,56]) ----
    const int ib  = (q4 << 3) - n + 32;
    const int dwb = ib >> 1;
    const int sh  = (ib & 1) << 4;
    const unsigned* rp = (const unsigned*)(synEb + (size_t)c * SROWP) + dwb;
    bf16x8 bfrag[NT];
    #pragma unroll
    for (int m = 0; m < NT; ++m) {            // max dword = 28+128+4 = 160 < 164
        unsigned w0 = rp[(m << 4) + 0], w1 = rp[(m << 4) + 1], w2 = rp[(m << 4) + 2],
                 w3 = rp[(m << 4) + 3], w4 = rp[(m << 4) + 4];
        union { unsigned dd[4]; bf16x8 v; } B;
        B.dd[0] = (unsigned)((((unsigned long long)w1 << 32) | w0) >> sh);
        B.dd[1] = (unsigned)((((unsigned long long)w2 << 32) | w1) >> sh);
        B.dd[2] = (unsigned)((((unsigned long long)w3 << 32) | w2) >> sh);
        B.dd[3] = (unsigned)((((unsigned long long)w4 << 32) | w3) >> sh);
        bfrag[m] = B.v;
    }

    // per-lane A base: u16 idx = c*LPAD + Lb + 16n + 8q4 (+ it*1024 + 256s + 32m)
    const unsigned short* xrow = xT + (size_t)c * LPAD + Lb + (n << 4) + (q4 << 3);

    #pragma unroll
    for (int it = 0; it < 2; ++it) {
        const unsigned short* xr = xrow + (it << 10);
        f32x4 acc[4];
        #pragma unroll
        for (int s = 0; s < 4; ++s) acc[s] = (f32x4){0.f, 0.f, 0.f, 0.f};
        #pragma unroll
        for (int m = 0; m < NT; ++m) {
            #pragma unroll
            for (int s = 0; s < 4; ++s) {     // 4 independent acc chains
                union { int4 i4; bf16x8 v; } A;
                A.i4 = *(const int4*)(xr + (s << 8) + (m << 5));   // max idx 8463 < 8512
                acc[s] = __builtin_amdgcn_mfma_f32_16x16x32_bf16(A.v, bfrag[m], acc[s], 0, 0, 0);
            }
        }
        float* o = out + (size_t)c * LL + Lb + (it << 10) + (q4 << 6) + n;
        #pragma unroll
        for (int s = 0; s < 4; ++s) {
            #pragma unroll
            for (int r = 0; r < 4; ++r) o[(s << 8) + (r << 4)] = acc[s][r];  // 4x64B segs
        }
    }
}

// ================== fallback path (R5, harness-verified, 53 us) ==================
static __device__ __forceinline__ void stage_fb(const float* __restrict__ x,
                                                unsigned short (*buf)[ROWS],
                                                int W0, int c0, int t) {
    #pragma unroll
    for (int k = 0; k < 3; ++k) {
        int pp = (k << 8) + t;
        if (pp < 672) {
            int lg = W0 + (pp << 1) - 128;
            const float* sp = x + (size_t)lg * CC + c0;
            float4 a = make_float4(0.f, 0.f, 0.f, 0.f);
            float4 b = make_float4(0.f, 0.f, 0.f, 0.f);
            if ((unsigned)lg       < (unsigned)LL) a = *(const float4*)sp;
            if ((unsigned)(lg + 1) < (unsigned)LL) b = *(const float4*)(sp + CC);
            int gq = pp >> 2;
            int gp = gq ^ ((gq >> 3) & 7);
            int dw = (gp << 2) | (pp & 3);
            const float* pe = (const float*)&a;
            const float* po = (const float*)&b;
            #pragma unroll
            for (int c2 = 0; c2 < 4; ++c2) {
                unsigned val = (unsigned)f2bf(pe[c2]) | ((unsigned)f2bf(po[c2]) << 16);
                ((unsigned*)buf[c2])[dw] = val;
            }
        }
    }
}

__global__ __launch_bounds__(256, 4) void fused_conv_fb(const float* __restrict__ x,
                                                        const unsigned short* __restrict__ synEb,
                                                        float* __restrict__ out) {
    __shared__ alignas(16) unsigned short xch[2][NCH][ROWS];
    __shared__ alignas(16) unsigned short synD[NCH][2][SROWP];
    const int t = threadIdx.x;
    const int d  = blockIdx.x;
    const int cg = ((d & 7) << 6) | (d >> 4);
    const int c0 = cg << 2;
    const int L0 = ((d >> 3) & 1) << 12;
    const int ci = t >> 6;
    const int ln = t & 63;
    const int n  = ln & 15, q4 = ln >> 4;
    const int gbase = (n << 1) + q4;
    const int ib  = (q4 << 3) - n + 32;
    const int par = ib & 1;
    const int e0  = (ib - par) >> 1;

    for (int u = t; u < NCH * 2 * SROWP; u += 256) {
        int ci2 = u / (2 * SROWP);
        int rem = u - ci2 * (2 * SROWP);
        int p   = (rem >= SROWP) ? 1 : 0;
        int idx = rem - (p ? SROWP : 0);
        int src = idx + p;
        if (src > SROWP - 1) src = SROWP - 1;
        synD[ci2][p][idx] = synEb[(size_t)(c0 + ci2) * SROWP + src];
    }
    stage_fb(x, xch[0], L0, c0, t);
    __syncthreads();

    bf16x8 bfrag[NT];
    {
        const unsigned* bp = (const unsigned*)(synD[ci][par]) + e0;
        #pragma unroll
        for (int m = 0; m < NT; ++m) {
            union { unsigned dd[4]; bf16x8 v; } B;
            B.dd[0] = bp[(m << 4) + 0];
            B.dd[1] = bp[(m << 4) + 1];
            B.dd[2] = bp[(m << 4) + 2];
            B.dd[3] = bp[(m << 4) + 3];
            bfrag[m] = B.v;
        }
    }

    for (int w = 0; w < NW; ++w) {
        const int cur = w & 1;
        const int W0  = L0 + (w << 10);
        const char* xrow = (const char*)xch[cur][ci];
        f32x4 acc[4];
        #pragma unroll
        for (int s = 0; s < 4; ++s) acc[s] = (f32x4){0.f, 0.f, 0.f, 0.f};
        #pragma unroll
        for (int m = 0; m < NT; ++m) {
            #pragma unroll
            for (int s = 0; s < 4; ++s) {
                int g  = gbase + (s << 5) + (m << 2);
                int gp = g ^ ((g >> 3) & 7);
                union { int4 i4; bf16x8 v; } A;
                A.i4 = *(const int4*)(xrow + (gp << 4));
                acc[s] = __builtin_amdgcn_mfma_f32_16x16x32_bf16(A.v, bfrag[m], acc[s], 0, 0, 0);
            }
        }
        float* o = out + (size_t)(c0 + ci) * LL + W0 + (q4 << 6) + n;
        #pragma unroll
        for (int s = 0; s < 4; ++s) {
            #pragma unroll
            for (int r = 0; r < 4; ++r) o[(s << 8) + (r << 4)] = acc[s][r];
        }
        if (w + 1 < NW) stage_fb(x, xch[cur ^ 1], W0 + 1024, c0, t);
        __syncthreads();
    }
}

// ------------------------------------------------------------------- launch
extern "C" void kernel_launch(void* const* d_in, const int* in_sizes, int n_in,
                              void* d_out, int out_size, void* d_ws, size_t ws_size,
                              hipStream_t stream) {
    const float* x    = (const float*)d_in[0];
    const int*   Yt   = (const int*)  d_in[1];
    const float* g    = (const float*)d_in[2];
    const float* kern = (const float*)d_in[3];
    float* out = (float*)d_out;
    const int ny = in_sizes[1];

    const size_t synBytes = (size_t)CC * SROWP * 2;            // 1.34 MB
    const size_t xTBytes  = (size_t)CC * LPAD * 2;             // 34.9 MB
    unsigned short* synEb = (unsigned short*)d_ws;
    unsigned short* xT    = (unsigned short*)((char*)d_ws + synBytes);

    synb_kernel<<<CC / 4, 256, 0, stream>>>(g, kern, Yt, ny, synEb);

    if (ws_size >= synBytes + xTBytes) {
        // fast path: one-time coalesced transpose, then barrier-free streaming conv
        xpose_kernel<<<dim3(LTILES, CC / 64), 256, 0, stream>>>(x, xT);
        conv_stream<<<dim3(LL / 2048, CC / 4), 256, 0, stream>>>(xT, synEb, out);
    } else {
        // workspace too small: harness-verified fused fallback
        fused_conv_fb<<<1024, 256, 0, stream>>>(x, synEb, out);
    }
}

// Round 7
// 140.788 us; speedup vs baseline: 1.1914x; 1.1914x over previous
//
#include <hip/hip_runtime.h>

#define LL   8192   // sequence length
#define CC   2048   // channels
#define FF   128    // inner dim of g@kernel
#define KK   257    // taps
#define PAD  128    // (KK-1)/2

#define SROW 320    // synEb row: 32 zeros | 257 taps | 31 zeros (u16 idx = k+32)
#define NT   18     // K-steps of 16 -> covers K in [0,288)

#define ROWS 1288   // xch LDS row in ushorts (2576 B: %16==0)
#define SRP  328    // synL LDS row in ushorts (656 B = 164 dwords; headroom for base+4 reads)

typedef __bf16 bf16x8 __attribute__((ext_vector_type(8)));
typedef float  f32x16 __attribute__((ext_vector_type(16)));

static __device__ __forceinline__ unsigned short f2bf(float f) {
    unsigned u = __float_as_uint(f);
    u = (u + 0x7fffu + ((u >> 16) & 1u)) >> 16;   // RNE
    return (unsigned short)u;
}

// Build synEb[c][320] bf16: zeros | g[c,:]@kernel[:,k] | zeros, with the
// Yt-row override folded in as a delta kernel (tap=1 at k=128) so the conv
// reproduces out[c,l] = x[l,c] exactly for flagged channels.
__global__ __launch_bounds__(256) void synb_kernel(const float* __restrict__ g,
                                                   const float* __restrict__ kern,
                                                   const int* __restrict__ Yt, int ny,
                                                   unsigned short* __restrict__ synEb) {
    __shared__ int sfl[4];
    const int c0 = blockIdx.x * 4;
    const int t  = threadIdx.x;
    if (t < 4) sfl[t] = 0;
    __syncthreads();
    for (int i = t; i < ny; i += 256) {
        int y = Yt[i];
        #pragma unroll
        for (int ii = 0; ii < 4; ++ii) if (y == c0 + ii) sfl[ii] = 1;
    }
    __syncthreads();
    const float* g0 = g + (size_t)(c0 + 0) * FF;
    const float* g1 = g + (size_t)(c0 + 1) * FF;
    const float* g2 = g + (size_t)(c0 + 2) * FF;
    const float* g3 = g + (size_t)(c0 + 3) * FF;
    const int fl0 = sfl[0], fl1 = sfl[1], fl2 = sfl[2], fl3 = sfl[3];
    for (int p = t; p < SROW; p += 256) {
        const int kk = p - 32;
        float a0 = 0.f, a1 = 0.f, a2 = 0.f, a3 = 0.f;
        const bool inr = (kk >= 0) && (kk < KK);
        if (inr) {
            #pragma unroll 8
            for (int f = 0; f < FF; ++f) {
                float kv = kern[f * KK + kk];      // coalesced across p
                a0 += kv * g0[f];
                a1 += kv * g1[f];
                a2 += kv * g2[f];
                a3 += kv * g3[f];
            }
        }
        float dlt = (kk == PAD) ? 1.f : 0.f;
        float v0 = inr ? (fl0 ? dlt : a0) : 0.f;
        float v1 = inr ? (fl1 ? dlt : a1) : 0.f;
        float v2 = inr ? (fl2 ? dlt : a2) : 0.f;
        float v3 = inr ? (fl3 ? dlt : a3) : 0.f;
        synEb[(size_t)(c0 + 0) * SROW + p] = f2bf(v0);
        synEb[(size_t)(c0 + 1) * SROW + p] = f2bf(v1);
        synEb[(size_t)(c0 + 2) * SROW + p] = f2bf(v2);
        synEb[(size_t)(c0 + 3) * SROW + p] = f2bf(v3);
    }
}

// Fused transpose + depthwise Toeplitz-MFMA conv (session-best R0 structure,
// verified 48 us) with two additive, counter-targeted changes:
//  1. XCD slab remap: the 128 blocks that share x cache lines (16 ch-groups x
//     8 l-windows) all land on ONE XCD's L2 (dispatch round-robins linear id
//     over 8 XCDs), so each 128B x-line is fetched into one L2, not up to 8.
//  2. Non-temporal out-stores: out is write-once, never re-read -> keep the
//     65 MB of stores from evicting x lines in L2.
__global__ __launch_bounds__(256) void fused_conv(const float* __restrict__ x,
                                                  const unsigned short* __restrict__ synEb,
                                                  float* __restrict__ out) {
    __shared__ alignas(16) unsigned short xch[16][ROWS];   // 41.2 KB
    __shared__ alignas(16) unsigned short synL[16][SRP];   // 10.5 KB
    const int t  = threadIdx.x;

    // ---- XCD slab remap (bijective on [0,1024)) ----
    // linear dispatch id d = by*8 + bx -> XCD r = d&7 (round-robin).
    // Give XCD r the channel slab [256r, 256r+256): cg in [16r,16r+16), all 8
    // l-windows. Within-XCD index i = d>>3: cg = 16r + (i&15), wl = i>>4.
    const int d  = (blockIdx.y << 3) | blockIdx.x;
    const int r_ = d & 7, i_ = d >> 3;
    const int W0 = (i_ >> 4) << 10;           // window base (l of output 0)
    const int c0 = ((r_ << 4) | (i_ & 15)) << 4;

    // ---- stage syn rows (16 x 160 dwords, coalesced) ----
    {
        const int rw = t >> 4;                // 0..15 channel row
        const int u  = t & 15;
        const unsigned* src = (const unsigned*)(synEb + (size_t)(c0 + rw) * SROW);
        unsigned* dst = (unsigned*)(synL[rw]);
        #pragma unroll
        for (int k = 0; k < 10; ++k) dst[u + (k << 4)] = src[u + (k << 4)];
    }

    // ---- stage x window: logical p in [0,1280), xpad[p] = x[W0+p-128][c] ----
    #pragma unroll
    for (int k = 0; k < 10; ++k) {
        int pidx = (k << 8) + t;              // [0,2560)
        int ch4  = pidx & 3;                  // float4 channel quad
        int pp   = pidx >> 2;                 // dword (l-pair) index [0,640)
        int lg   = W0 + (pp << 1) - 128;      // global l of even element
        const float* sp = x + (size_t)lg * CC + c0 + (ch4 << 2);
        float4 ve = make_float4(0.f, 0.f, 0.f, 0.f);
        float4 vo = make_float4(0.f, 0.f, 0.f, 0.f);
        if ((unsigned)lg       < (unsigned)LL) ve = *(const float4*)sp;        // 16 segs/instr
        if ((unsigned)(lg + 1) < (unsigned)LL) vo = *(const float4*)(sp + CC);
        int gq = pp >> 2;                     // granule (8 u16)
        int gp = gq ^ ((gq >> 3) & 7);        // XOR swizzle (R2-verified)
        int dw = (gp << 2) | (pp & 3);        // dword slot within row
        const float* pe = (const float*)&ve;
        const float* po = (const float*)&vo;
        #pragma unroll
        for (int c2 = 0; c2 < 4; ++c2) {
            unsigned val = (unsigned)f2bf(pe[c2]) | ((unsigned)f2bf(po[c2]) << 16);
            ((unsigned*)xch[(ch4 << 2) + c2])[dw] = val;
        }
    }
    __syncthreads();

    const int w = t >> 6, ln = t & 63;
    const int j = ln & 31, q = ln >> 5;
    const int bb  = (q << 4) - 2 * j + 64;    // byte base of bfrag m=0 (in [2,80], even)
    const int dwb = bb >> 2;                  // dword base at m=0
    const int sh  = (bb & 2) << 3;            // residual funnel shift: 0 or 16 bits
    const int gb  = (j << 2) + q;             // A granule base

    for (int cc = 0; cc < 4; ++cc) {
        const int ci = (w << 2) + cc;
        // ---- bfrag build: 5 dwords + 64-bit funnel by sh (v_alignbit) ----
        // B.u[r] = synL[ci] u16 index (16m + 8q + r - j + 32); bytes [b, b+16),
        // b = 32m + bb. dword base = dwb + 8m; sh is m-invariant.
        bf16x8 bfrag[NT];
        const unsigned* rp = (const unsigned*)(synL[ci]);
        #pragma unroll
        for (int m = 0; m < NT; ++m) {
            int base = dwb + (m << 3);
            unsigned w0 = rp[base + 0], w1 = rp[base + 1], w2 = rp[base + 2],
                     w3 = rp[base + 3], w4 = rp[base + 4];
            union { unsigned d[4]; bf16x8 v; } B;
            B.d[0] = (unsigned)((((unsigned long long)w1 << 32) | w0) >> sh);
            B.d[1] = (unsigned)((((unsigned long long)w2 << 32) | w1) >> sh);
            B.d[2] = (unsigned)((((unsigned long long)w3 << 32) | w2) >> sh);
            B.d[3] = (unsigned)((((unsigned long long)w4 << 32) | w3) >> sh);
            bfrag[m] = B.v;
        }
        // ---- 18 MFMA over the Toeplitz K-extent ----
        f32x16 acc;
        #pragma unroll
        for (int r = 0; r < 16; ++r) acc[r] = 0.f;
        #pragma unroll
        for (int m = 0; m < NT; ++m) {
            int gq = gb + (m << 1);
            int gp = gq ^ ((gq >> 3) & 7);
            union { int4 i4; bf16x8 v; } A;
            A.i4 = *(const int4*)(&xch[ci][gp << 3]);
            acc = __builtin_amdgcn_mfma_f32_32x32x16_bf16(A.v, bfrag[m], acc, 0, 0, 0);
        }
        // ---- store: D col=lane&31, row=(r&3)+8*(r>>2)+4q; non-temporal ----
        float* o = out + (size_t)(c0 + ci) * LL + W0 + j;
        #pragma unroll
        for (int r = 0; r < 16; ++r) {
            int row = (r & 3) + ((r >> 2) << 3) + (q << 2);
            __builtin_nontemporal_store(acc[r], &o[row << 5]);  // 2 x 128B segs/instr
        }
    }
}

// ------------------------------------------------------------------- launch
extern "C" void kernel_launch(void* const* d_in, const int* in_sizes, int n_in,
                              void* d_out, int out_size, void* d_ws, size_t ws_size,
                              hipStream_t stream) {
    const float* x    = (const float*)d_in[0];
    const int*   Yt   = (const int*)  d_in[1];
    const float* g    = (const float*)d_in[2];
    const float* kern = (const float*)d_in[3];
    float* out = (float*)d_out;
    const int ny = in_sizes[1];

    unsigned short* synEb = (unsigned short*)d_ws;   // 2048*320*2 = 1.31 MB

    synb_kernel<<<CC / 4, 256, 0, stream>>>(g, kern, Yt, ny, synEb);
    fused_conv<<<dim3(LL / 1024, CC / 16), 256, 0, stream>>>(x, synEb, out);
}